// Round 1
// baseline (498.371 us; speedup 1.0000x reference)
//
#include <hip/hip_runtime.h>
#include <hip/hip_bf16.h>

#define DIM 512
#define BB 8
#define LL 8192
#define ML (BB * LL)  // 65536 rows

typedef __attribute__((ext_vector_type(4))) float f32x4;
typedef __attribute__((ext_vector_type(8))) short short8;

__device__ __forceinline__ void gl_lds16(const __hip_bfloat16* g, __hip_bfloat16* l) {
  __builtin_amdgcn_global_load_lds(
      (const __attribute__((address_space(1))) void*)g,
      (__attribute__((address_space(3))) void*)l, 16, 0, 0);
}

__device__ __forceinline__ unsigned short bf16_bits(float f) {
  __hip_bfloat16 h = __float2bfloat16(f);
  return *reinterpret_cast<unsigned short*>(&h);
}

// ---------------- depthwise causal conv (K=4, left pad 3) + cast to bf16 ----
__global__ void conv_cast_kernel(const float* __restrict__ x,
                                 const float* __restrict__ cw,
                                 const float* __restrict__ cb,
                                 __hip_bfloat16* __restrict__ xc) {
  const int tid = blockIdx.x * 256 + threadIdx.x;
  const int d = (tid & 127) << 2;  // 0..508 step 4
  const int bl = tid >> 7;
  if (bl >= ML) return;
  const int l = bl & (LL - 1);
  float4 acc = *(const float4*)(cb + d);
#pragma unroll
  for (int k = 0; k < 4; ++k) {
    const int ll = l - 3 + k;
    if (ll >= 0) {
      const float4 xv = *(const float4*)(x + (size_t)(bl - 3 + k) * DIM + d);
      acc.x += xv.x * cw[(d + 0) * 4 + k];
      acc.y += xv.y * cw[(d + 1) * 4 + k];
      acc.z += xv.z * cw[(d + 2) * 4 + k];
      acc.w += xv.w * cw[(d + 3) * 4 + k];
    }
  }
  ushort4 o;
  o.x = bf16_bits(acc.x);
  o.y = bf16_bits(acc.y);
  o.z = bf16_bits(acc.z);
  o.w = bf16_bits(acc.w);
  *(ushort4*)((unsigned short*)xc + (size_t)bl * DIM + d) = o;
}

// ---------------- weight prep: cast q_w [N,K]; transpose-cast mem_w1/2 ------
__global__ void prep_weights_kernel(const float* __restrict__ qw,
                                    const float* __restrict__ w1,
                                    const float* __restrict__ w2,
                                    __hip_bfloat16* __restrict__ wq,
                                    __hip_bfloat16* __restrict__ w1t,
                                    __hip_bfloat16* __restrict__ w2t) {
  const int i = blockIdx.x * 256 + threadIdx.x;  // 0..262143
  const int r = i >> 9;   // k index of mem_w*
  const int c = i & 511;  // n index
  wq[i] = __float2bfloat16(qw[i]);  // q_w already [out=n, in=k]
  w1t[(size_t)c * DIM + r] = __float2bfloat16(w1[i]);
  w2t[(size_t)c * DIM + r] = __float2bfloat16(w2[i]);
}

// ---------------- GEMM: C[M,N] = A[M,K](bf16) @ Bt[N,K](bf16)^T, f32 acc ----
// 128x128 tile, BK=32, 4 waves (2x2), each wave 64x64 (4x4 of 16x16 MFMA).
// EPI: 0 = store f32; 1 = exact GELU -> bf16; 2 = add residual Q (bf16) -> f32
template <int EPI>
__global__ __launch_bounds__(256) void gemm_bt(
    const __hip_bfloat16* __restrict__ A, const __hip_bfloat16* __restrict__ Bt,
    float* __restrict__ Cf, __hip_bfloat16* __restrict__ Cb,
    const __hip_bfloat16* __restrict__ Q, int M, int N, int K) {
  __shared__ __hip_bfloat16 sA[128 * 32];
  __shared__ __hip_bfloat16 sB[128 * 32];
  const int nbn = N >> 7;
  const int bm = blockIdx.x / nbn;
  const int bn = blockIdx.x - bm * nbn;
  const int tid = threadIdx.x;
  const int wv = tid >> 6, ln = tid & 63;
  const int wr = wv >> 1, wc = wv & 1;
  const int idx = ln & 15, kg = ln >> 4;
  const size_t rowA = (size_t)bm * 128, rowB = (size_t)bn * 128;

  f32x4 acc[4][4] = {};

  // staging geometry: slot s = (wv*2+i)*64 + ln covers LDS bytes [s*16, s*16+16)
  // row r = s>>2 (0..127), k-chunk = (s&3)*8
  const int r0 = (wv * 2 + 0) * 16 + (ln >> 2);
  const int r1 = (wv * 2 + 1) * 16 + (ln >> 2);
  const int kcl = (ln & 3) * 8;
  __hip_bfloat16* lbA0 = sA + (wv * 2 + 0) * 512;  // wave-uniform LDS bases
  __hip_bfloat16* lbA1 = sA + (wv * 2 + 1) * 512;
  __hip_bfloat16* lbB0 = sB + (wv * 2 + 0) * 512;
  __hip_bfloat16* lbB1 = sB + (wv * 2 + 1) * 512;

  for (int k0 = 0; k0 < K; k0 += 32) {
    gl_lds16(A + (rowA + r0) * K + k0 + kcl, lbA0);
    gl_lds16(A + (rowA + r1) * K + k0 + kcl, lbA1);
    gl_lds16(Bt + (rowB + r0) * K + k0 + kcl, lbB0);
    gl_lds16(Bt + (rowB + r1) * K + k0 + kcl, lbB1);
    __syncthreads();  // compiler drains vmcnt(0) before s_barrier

    short8 af[4], bfv[4];
#pragma unroll
    for (int mi = 0; mi < 4; ++mi)
      af[mi] = *(const short8*)(sA + (wr * 64 + mi * 16 + idx) * 32 + kg * 8);
#pragma unroll
    for (int ni = 0; ni < 4; ++ni)
      bfv[ni] = *(const short8*)(sB + (wc * 64 + ni * 16 + idx) * 32 + kg * 8);
#pragma unroll
    for (int mi = 0; mi < 4; ++mi)
#pragma unroll
      for (int ni = 0; ni < 4; ++ni)
        acc[mi][ni] = __builtin_amdgcn_mfma_f32_16x16x32_bf16(
            af[mi], bfv[ni], acc[mi][ni], 0, 0, 0);
    __syncthreads();
  }

  // epilogue: C/D layout col = lane&15, row = (lane>>4)*4 + j  [m89-verified]
  const int cr0 = (int)rowA + wr * 64;
  const int cc0 = (int)rowB + wc * 64;
#pragma unroll
  for (int mi = 0; mi < 4; ++mi) {
#pragma unroll
    for (int ni = 0; ni < 4; ++ni) {
#pragma unroll
      for (int j = 0; j < 4; ++j) {
        const int r = cr0 + mi * 16 + kg * 4 + j;
        const int c = cc0 + ni * 16 + idx;
        const size_t off = (size_t)r * N + c;
        const float v = acc[mi][ni][j];
        if (EPI == 0) {
          Cf[off] = v;
        } else if (EPI == 1) {
          const float ge = 0.5f * v * (1.0f + erff(v * 0.70710678118654752f));
          Cb[off] = __float2bfloat16(ge);
        } else {
          Cf[off] = v + __bfloat162float(Q[off]);
        }
      }
    }
  }
}

// ---------------- row-wise L2 normalize: C1 f32 -> q bf16 -------------------
__global__ void rownorm_kernel(const float* __restrict__ C1,
                               __hip_bfloat16* __restrict__ q) {
  const int row = blockIdx.x * 4 + (threadIdx.x >> 6);
  const int ln = threadIdx.x & 63;
  const float* rp = C1 + (size_t)row * DIM;
  const float4 v0 = *(const float4*)(rp + ln * 4);
  const float4 v1 = *(const float4*)(rp + 256 + ln * 4);
  float ss = v0.x * v0.x + v0.y * v0.y + v0.z * v0.z + v0.w * v0.w +
             v1.x * v1.x + v1.y * v1.y + v1.z * v1.z + v1.w * v1.w;
#pragma unroll
  for (int off = 32; off > 0; off >>= 1) ss += __shfl_xor(ss, off, 64);
  const float scale = 1.0f / fmaxf(sqrtf(ss), 1e-12f);
  ushort4 o0, o1;
  o0.x = bf16_bits(v0.x * scale);
  o0.y = bf16_bits(v0.y * scale);
  o0.z = bf16_bits(v0.z * scale);
  o0.w = bf16_bits(v0.w * scale);
  o1.x = bf16_bits(v1.x * scale);
  o1.y = bf16_bits(v1.y * scale);
  o1.z = bf16_bits(v1.z * scale);
  o1.w = bf16_bits(v1.w * scale);
  unsigned short* qp = (unsigned short*)q + (size_t)row * DIM;
  *(ushort4*)(qp + ln * 4) = o0;
  *(ushort4*)(qp + 256 + ln * 4) = o1;
}

extern "C" void kernel_launch(void* const* d_in, const int* in_sizes, int n_in,
                              void* d_out, int out_size, void* d_ws,
                              size_t ws_size, hipStream_t stream) {
  const float* x = (const float*)d_in[0];
  const float* cw = (const float*)d_in[1];
  const float* cb = (const float*)d_in[2];
  const float* qw = (const float*)d_in[3];
  const float* w1 = (const float*)d_in[4];
  const float* w2 = (const float*)d_in[5];
  float* out = (float*)d_out;

  // ws layout (total ~135.8 MB):
  //   [0, 64Mi)    x_conv bf16, reused as g (gelu output) after GEMM1
  //   [64Mi,128Mi) q bf16
  //   [128Mi, ...) wq, w1t, w2t bf16 (512 KB each)
  char* ws = (char*)d_ws;
  __hip_bfloat16* xconv = (__hip_bfloat16*)ws;
  __hip_bfloat16* qb = (__hip_bfloat16*)(ws + (size_t)67108864);
  __hip_bfloat16* wq = (__hip_bfloat16*)(ws + (size_t)134217728);
  __hip_bfloat16* w1t = wq + DIM * DIM;
  __hip_bfloat16* w2t = w1t + DIM * DIM;
  __hip_bfloat16* g = xconv;  // alias: x_conv dead after GEMM1

  const int gemm_grid = (ML / 128) * (DIM / 128);  // 2048

  conv_cast_kernel<<<ML * (DIM / 4) / 256, 256, 0, stream>>>(x, cw, cb, xconv);
  prep_weights_kernel<<<DIM * DIM / 256, 256, 0, stream>>>(qw, w1, w2, wq, w1t,
                                                           w2t);
  // GEMM1: C1 = x_conv @ q_w^T  -> d_out used as f32 scratch
  gemm_bt<0><<<gemm_grid, 256, 0, stream>>>(xconv, wq, out, nullptr, nullptr,
                                            ML, DIM, DIM);
  // q = l2norm(C1) -> bf16
  rownorm_kernel<<<ML / 4, 256, 0, stream>>>(out, qb);
  // g = gelu(q @ mem_w1) -> bf16 (into x_conv's region)
  gemm_bt<1><<<gemm_grid, 256, 0, stream>>>(qb, w1t, nullptr, g, nullptr, ML,
                                            DIM, DIM);
  // out = q + g @ mem_w2 -> f32
  gemm_bt<2><<<gemm_grid, 256, 0, stream>>>(g, w2t, out, nullptr, qb, ML, DIM,
                                            DIM);
}

// Round 3
// 315.387 us; speedup vs baseline: 1.5802x; 1.5802x over previous
//
#include <hip/hip_runtime.h>
#include <hip/hip_bf16.h>

#define DIM 512
#define BB 8
#define LL 8192
#define ML (BB * LL)  // 65536 rows

typedef __attribute__((ext_vector_type(4))) float f32x4;
typedef __attribute__((ext_vector_type(8))) short short8;

__device__ __forceinline__ void gl_lds16(const __hip_bfloat16* g, __hip_bfloat16* l) {
  __builtin_amdgcn_global_load_lds(
      (const __attribute__((address_space(1))) void*)g,
      (__attribute__((address_space(3))) void*)l, 16, 0, 0);
}

__device__ __forceinline__ unsigned short bf16_bits(float f) {
  __hip_bfloat16 h = __float2bfloat16(f);
  return *reinterpret_cast<unsigned short*>(&h);
}

// ---------------- zero the row-sumsq accumulator (deterministic, no memset) -
__global__ void zero_ss(float* __restrict__ ss) {
  ss[blockIdx.x * 256 + threadIdx.x] = 0.0f;
}

// ---------------- depthwise causal conv (K=4, left pad 3) + cast to bf16 ----
// cwt is pre-transposed [k][d] so weight loads are lane-coalesced float4.
__global__ void conv_cast_kernel(const float* __restrict__ x,
                                 const float* __restrict__ cwt,
                                 const float* __restrict__ cb,
                                 __hip_bfloat16* __restrict__ xc) {
  const int tid = blockIdx.x * 256 + threadIdx.x;
  const int d = (tid & 127) << 2;  // 0..508 step 4
  const int bl = tid >> 7;
  const int l = bl & (LL - 1);
  float4 acc = *(const float4*)(cb + d);
  float4 w[4];
#pragma unroll
  for (int k = 0; k < 4; ++k) w[k] = *(const float4*)(cwt + k * DIM + d);
#pragma unroll
  for (int k = 0; k < 4; ++k) {
    if (l - 3 + k >= 0) {
      const float4 xv = *(const float4*)(x + (size_t)(bl - 3 + k) * DIM + d);
      acc.x += xv.x * w[k].x;
      acc.y += xv.y * w[k].y;
      acc.z += xv.z * w[k].z;
      acc.w += xv.w * w[k].w;
    }
  }
  ushort4 o;
  o.x = bf16_bits(acc.x);
  o.y = bf16_bits(acc.y);
  o.z = bf16_bits(acc.z);
  o.w = bf16_bits(acc.w);
  *(ushort4*)((unsigned short*)xc + (size_t)bl * DIM + d) = o;
}

// ---------------- weight prep: cast (or transpose-cast) one 512x512 weight --
// Optionally also emits transposed conv weight cwt[k][d] (f32).
__global__ void prep_w(const float* __restrict__ src,
                       __hip_bfloat16* __restrict__ dst, int transpose,
                       const float* __restrict__ cw, float* __restrict__ cwt) {
  const int i = blockIdx.x * 256 + threadIdx.x;  // 0..262143
  if (transpose)
    dst[(size_t)(i & 511) * DIM + (i >> 9)] = __float2bfloat16(src[i]);
  else
    dst[i] = __float2bfloat16(src[i]);
  if (cwt != nullptr && i < DIM * 4) cwt[(i & 3) * DIM + (i >> 2)] = cw[i];
}

// ---------------- GEMM: C[M,N] = A[M,K](bf16) @ Bt[N,K](bf16)^T, f32 acc ----
// 128x128 tile, BK=32, 4 waves (2x2), each wave 64x64 (4x4 of 16x16 MFMA).
// EPI 0: write C1 bf16 + per-row sum-of-squares atomics into ss
// EPI 1: v *= 1/max(sqrt(ss[r]),eps); exact GELU -> bf16
// EPI 2: out f32 = v + (1/max(sqrt(ss[r]),eps)) * C1_bf16[off]  (residual q)
template <int EPI>
__global__ __launch_bounds__(256) void gemm_bt(
    const __hip_bfloat16* __restrict__ A, const __hip_bfloat16* __restrict__ Bt,
    float* __restrict__ Cf, __hip_bfloat16* __restrict__ Cb,
    const __hip_bfloat16* __restrict__ C1, float* __restrict__ ss, int M,
    int N, int K) {
  __shared__ __hip_bfloat16 sA[128 * 32];
  __shared__ __hip_bfloat16 sB[128 * 32];
  const int nbn = N >> 7;
  const int bm = blockIdx.x / nbn;
  const int bn = blockIdx.x - bm * nbn;
  const int tid = threadIdx.x;
  const int wv = tid >> 6, ln = tid & 63;
  const int wr = wv >> 1, wc = wv & 1;
  const int idx = ln & 15, kg = ln >> 4;
  const size_t rowA = (size_t)bm * 128, rowB = (size_t)bn * 128;

  f32x4 acc[4][4] = {};

  // staging: slot s = (wv*2+i)*64 + ln covers LDS bytes [s*16, s*16+16)
  const int r0 = (wv * 2 + 0) * 16 + (ln >> 2);
  const int r1 = (wv * 2 + 1) * 16 + (ln >> 2);
  const int kcl = (ln & 3) * 8;
  __hip_bfloat16* lbA0 = sA + (wv * 2 + 0) * 512;  // wave-uniform LDS bases
  __hip_bfloat16* lbA1 = sA + (wv * 2 + 1) * 512;
  __hip_bfloat16* lbB0 = sB + (wv * 2 + 0) * 512;
  __hip_bfloat16* lbB1 = sB + (wv * 2 + 1) * 512;

  for (int k0 = 0; k0 < K; k0 += 32) {
    gl_lds16(A + (rowA + r0) * K + k0 + kcl, lbA0);
    gl_lds16(A + (rowA + r1) * K + k0 + kcl, lbA1);
    gl_lds16(Bt + (rowB + r0) * K + k0 + kcl, lbB0);
    gl_lds16(Bt + (rowB + r1) * K + k0 + kcl, lbB1);
    __syncthreads();

    short8 af[4], bfv[4];
#pragma unroll
    for (int mi = 0; mi < 4; ++mi)
      af[mi] = *(const short8*)(sA + (wr * 64 + mi * 16 + idx) * 32 + kg * 8);
#pragma unroll
    for (int ni = 0; ni < 4; ++ni)
      bfv[ni] = *(const short8*)(sB + (wc * 64 + ni * 16 + idx) * 32 + kg * 8);
#pragma unroll
    for (int mi = 0; mi < 4; ++mi)
#pragma unroll
      for (int ni = 0; ni < 4; ++ni)
        acc[mi][ni] = __builtin_amdgcn_mfma_f32_16x16x32_bf16(
            af[mi], bfv[ni], acc[mi][ni], 0, 0, 0);
    __syncthreads();
  }

  // epilogue: C/D layout col = lane&15, row = (lane>>4)*4 + j  [m89-verified]
  const int cr0 = (int)rowA + wr * 64;
  const int cc0 = (int)rowB + wc * 64;
#pragma unroll
  for (int mi = 0; mi < 4; ++mi) {
#pragma unroll
    for (int j = 0; j < 4; ++j) {
      const int r = cr0 + mi * 16 + kg * 4 + j;
      if (EPI == 0) {
        float ps = 0.0f;
#pragma unroll
        for (int ni = 0; ni < 4; ++ni) {
          const float v = acc[mi][ni][j];
          ps += v * v;
          Cb[(size_t)r * N + cc0 + ni * 16 + idx] = __float2bfloat16(v);
        }
        ps += __shfl_xor(ps, 1, 64);
        ps += __shfl_xor(ps, 2, 64);
        ps += __shfl_xor(ps, 4, 64);
        ps += __shfl_xor(ps, 8, 64);
        if (idx == 0) atomicAdd(ss + r, ps);
      } else {
        const float sc = 1.0f / fmaxf(sqrtf(ss[r]), 1e-12f);
#pragma unroll
        for (int ni = 0; ni < 4; ++ni) {
          const size_t off = (size_t)r * N + cc0 + ni * 16 + idx;
          if (EPI == 1) {
            const float v = acc[mi][ni][j] * sc;
            const float ge =
                0.5f * v * (1.0f + erff(v * 0.70710678118654752f));
            Cb[off] = __float2bfloat16(ge);
          } else {
            Cf[off] = acc[mi][ni][j] + sc * __bfloat162float(C1[off]);
          }
        }
      }
    }
  }
}

extern "C" void kernel_launch(void* const* d_in, const int* in_sizes, int n_in,
                              void* d_out, int out_size, void* d_ws,
                              size_t ws_size, hipStream_t stream) {
  const float* x = (const float*)d_in[0];
  const float* cw = (const float*)d_in[1];
  const float* cb = (const float*)d_in[2];
  const float* qw = (const float*)d_in[3];
  const float* w1 = (const float*)d_in[4];
  const float* w2 = (const float*)d_in[5];
  float* out = (float*)d_out;

  // ws layout (high-water 135.54 MB, under proven-safe 135.79 MB):
  //   [0, 64Mi)        x_conv bf16, reused as g (gelu out) after GEMM1
  //   [64Mi, 128Mi)    C1 bf16 (pre-normalize q-GEMM output; lives to GEMM3)
  //   [128Mi, +512K)   weight slot A (bf16)
  //   [+512K, +1M)     weight slot B (bf16)
  //   [+1M, +1M+8K)    cwt f32 [4][512]
  //   [+1M+8K, +1.25M) ss f32 [ML] row sum-of-squares
  char* ws = (char*)d_ws;
  __hip_bfloat16* xconv = (__hip_bfloat16*)ws;
  __hip_bfloat16* C1 = (__hip_bfloat16*)(ws + (size_t)67108864);
  __hip_bfloat16* wA = (__hip_bfloat16*)(ws + (size_t)134217728);
  __hip_bfloat16* wB = wA + DIM * DIM;
  float* cwt = (float*)(ws + (size_t)134217728 + 1048576);
  float* ss = (float*)(ws + (size_t)134217728 + 1048576 + 8192);
  __hip_bfloat16* g = xconv;  // alias: x_conv dead after GEMM1

  const int gemm_grid = (ML / 128) * (DIM / 128);  // 2048

  zero_ss<<<ML / 256, 256, 0, stream>>>(ss);
  // prep: wA = qw (no transpose) + cwt; wB = w1^T
  prep_w<<<DIM * DIM / 256, 256, 0, stream>>>(qw, wA, 0, cw, cwt);
  prep_w<<<DIM * DIM / 256, 256, 0, stream>>>(w1, wB, 1, nullptr, nullptr);
  conv_cast_kernel<<<ML * (DIM / 4) / 256, 256, 0, stream>>>(x, cwt, cb, xconv);
  // GEMM1: C1 = x_conv @ q_w^T (bf16) + row sumsq -> ss
  gemm_bt<0><<<gemm_grid, 256, 0, stream>>>(xconv, wA, nullptr, C1, nullptr,
                                            ss, ML, DIM, DIM);
  // prep: wA = w2^T (slot A free after GEMM1)
  prep_w<<<DIM * DIM / 256, 256, 0, stream>>>(w2, wA, 1, nullptr, nullptr);
  // GEMM2: g = gelu(sc * (C1 @ w1)) -> bf16 (into x_conv's region)
  gemm_bt<1><<<gemm_grid, 256, 0, stream>>>(C1, wB, nullptr, g, nullptr, ss,
                                            ML, DIM, DIM);
  // GEMM3: out = sc*C1 + g @ w2 -> f32
  gemm_bt<2><<<gemm_grid, 256, 0, stream>>>(g, wA, out, nullptr, C1, ss, ML,
                                            DIM, DIM);
}

// Round 4
// 294.333 us; speedup vs baseline: 1.6932x; 1.0715x over previous
//
#include <hip/hip_runtime.h>
#include <hip/hip_bf16.h>

#define DIM 512
#define BB 8
#define LL 8192
#define ML (BB * LL)  // 65536 rows

typedef __attribute__((ext_vector_type(4))) float f32x4;
typedef __attribute__((ext_vector_type(8))) short short8;

__device__ __forceinline__ void gl_lds16(const __hip_bfloat16* g, __hip_bfloat16* l) {
  __builtin_amdgcn_global_load_lds(
      (const __attribute__((address_space(1))) void*)g,
      (__attribute__((address_space(3))) void*)l, 16, 0, 0);
}

__device__ __forceinline__ unsigned short bf16_bits(float f) {
  __hip_bfloat16 h = __float2bfloat16(f);
  return *reinterpret_cast<unsigned short*>(&h);
}

// ---------------- zero the row-sumsq accumulator (deterministic, no memset) -
__global__ void zero_ss(float* __restrict__ ss) {
  ss[blockIdx.x * 256 + threadIdx.x] = 0.0f;
}

// ---------------- depthwise causal conv (K=4, left pad 3) + cast to bf16 ----
__global__ void conv_cast_kernel(const float* __restrict__ x,
                                 const float* __restrict__ cwt,
                                 const float* __restrict__ cb,
                                 __hip_bfloat16* __restrict__ xc) {
  const int tid = blockIdx.x * 256 + threadIdx.x;
  const int d = (tid & 127) << 2;  // 0..508 step 4
  const int bl = tid >> 7;
  const int l = bl & (LL - 1);
  float4 acc = *(const float4*)(cb + d);
  float4 w[4];
#pragma unroll
  for (int k = 0; k < 4; ++k) w[k] = *(const float4*)(cwt + k * DIM + d);
#pragma unroll
  for (int k = 0; k < 4; ++k) {
    if (l - 3 + k >= 0) {
      const float4 xv = *(const float4*)(x + (size_t)(bl - 3 + k) * DIM + d);
      acc.x += xv.x * w[k].x;
      acc.y += xv.y * w[k].y;
      acc.z += xv.z * w[k].z;
      acc.w += xv.w * w[k].w;
    }
  }
  ushort4 o;
  o.x = bf16_bits(acc.x);
  o.y = bf16_bits(acc.y);
  o.z = bf16_bits(acc.z);
  o.w = bf16_bits(acc.w);
  *(ushort4*)((unsigned short*)xc + (size_t)bl * DIM + d) = o;
}

// ---------------- weight prep: cast (or transpose-cast) one 512x512 weight --
__global__ void prep_w(const float* __restrict__ src,
                       __hip_bfloat16* __restrict__ dst, int transpose,
                       const float* __restrict__ cw, float* __restrict__ cwt) {
  const int i = blockIdx.x * 256 + threadIdx.x;  // 0..262143
  if (transpose)
    dst[(size_t)(i & 511) * DIM + (i >> 9)] = __float2bfloat16(src[i]);
  else
    dst[i] = __float2bfloat16(src[i]);
  if (cwt != nullptr && i < DIM * 4) cwt[(i & 3) * DIM + (i >> 2)] = cw[i];
}

// ---------------- GEMM: C[M,N] = A[M,K](bf16) @ Bt[N,K](bf16)^T, f32 acc ----
// 128x128 tile, BK=32, 4 waves (2x2), 2-phase double-buffered (T3-min),
// T2 both-sides XOR chunk-swizzle, T1 XCD-chunked block swizzle.
// EPI 0: write C1 bf16 + per-row sum-of-squares atomics into ss
// EPI 1: v *= 1/max(sqrt(ss[r]),eps); exact GELU -> bf16
// EPI 2: out f32 = v + (1/max(sqrt(ss[r]),eps)) * C1_bf16[off]  (residual q)
template <int EPI>
__global__ __launch_bounds__(256) void gemm_bt(
    const __hip_bfloat16* __restrict__ A, const __hip_bfloat16* __restrict__ Bt,
    float* __restrict__ Cf, __hip_bfloat16* __restrict__ Cb,
    const __hip_bfloat16* __restrict__ C1, float* __restrict__ ss, int M,
    int N, int K) {
  __shared__ __hip_bfloat16 sA[2][128 * 32];
  __shared__ __hip_bfloat16 sB[2][128 * 32];
  // T1: XCD-chunked swizzle (gridDim %8 == 0 here: 2048)
  const int nbn = N >> 7;
  const int bid = blockIdx.x;
  const int swz = (bid & 7) * (gridDim.x >> 3) + (bid >> 3);
  const int bm = swz / nbn;
  const int bn = swz - bm * nbn;
  const int tid = threadIdx.x;
  const int wv = tid >> 6, ln = tid & 63;
  const int wr = wv >> 1, wc = wv & 1;
  const int idx = ln & 15, kg = ln >> 4;
  const size_t rowA = (size_t)bm * 128, rowB = (size_t)bn * 128;

  f32x4 acc[4][4] = {};

  // staging: slot s = (wv*2+i)*64 + ln -> LDS bytes [s*16, s*16+16)
  // row = s>>2, chunk kc = s&3. T2: LDS slot (row,kc) holds global chunk
  // kc ^ ((row>>1)&3); for this slot map that is (ln&3)^((ln>>3)&3).
  const int r0 = (wv * 2 + 0) * 16 + (ln >> 2);
  const int r1 = (wv * 2 + 1) * 16 + (ln >> 2);
  const int kcl = (((ln & 3) ^ ((ln >> 3) & 3)) << 3);  // elements
  // read side: global chunk kg at row lives in LDS chunk kg ^ ((idx>>1)&3)
  const int kgx = ((kg ^ ((idx >> 1) & 3)) << 3);  // elements

  const int nt = K >> 5;  // 16 K-steps

  // prologue
  gl_lds16(A + (rowA + r0) * K + 0 + kcl, &sA[0][(wv * 2 + 0) * 512]);
  gl_lds16(A + (rowA + r1) * K + 0 + kcl, &sA[0][(wv * 2 + 1) * 512]);
  gl_lds16(Bt + (rowB + r0) * K + 0 + kcl, &sB[0][(wv * 2 + 0) * 512]);
  gl_lds16(Bt + (rowB + r1) * K + 0 + kcl, &sB[0][(wv * 2 + 1) * 512]);
  __syncthreads();

  int cur = 0;
  for (int t = 0; t < nt; ++t) {
    if (t + 1 < nt) {  // prefetch next K-step into the other buffer
      const int k0 = (t + 1) << 5;
      const int nxt = cur ^ 1;
      gl_lds16(A + (rowA + r0) * K + k0 + kcl, &sA[nxt][(wv * 2 + 0) * 512]);
      gl_lds16(A + (rowA + r1) * K + k0 + kcl, &sA[nxt][(wv * 2 + 1) * 512]);
      gl_lds16(Bt + (rowB + r0) * K + k0 + kcl, &sB[nxt][(wv * 2 + 0) * 512]);
      gl_lds16(Bt + (rowB + r1) * K + k0 + kcl, &sB[nxt][(wv * 2 + 1) * 512]);
    }
    short8 af[4], bfv[4];
#pragma unroll
    for (int mi = 0; mi < 4; ++mi)
      af[mi] =
          *(const short8*)(&sA[cur][(wr * 64 + mi * 16 + idx) * 32 + kgx]);
#pragma unroll
    for (int ni = 0; ni < 4; ++ni)
      bfv[ni] =
          *(const short8*)(&sB[cur][(wc * 64 + ni * 16 + idx) * 32 + kgx]);
    __builtin_amdgcn_s_setprio(1);
#pragma unroll
    for (int mi = 0; mi < 4; ++mi)
#pragma unroll
      for (int ni = 0; ni < 4; ++ni)
        acc[mi][ni] = __builtin_amdgcn_mfma_f32_16x16x32_bf16(
            af[mi], bfv[ni], acc[mi][ni], 0, 0, 0);
    __builtin_amdgcn_s_setprio(0);
    if (t + 1 < nt) __syncthreads();  // drains vmcnt(0): next buffer ready
    cur ^= 1;
  }

  // epilogue: C/D layout col = lane&15, row = (lane>>4)*4 + j  [m89-verified]
  const int cr0 = (int)rowA + wr * 64;
  const int cc0 = (int)rowB + wc * 64;
#pragma unroll
  for (int mi = 0; mi < 4; ++mi) {
#pragma unroll
    for (int j = 0; j < 4; ++j) {
      const int r = cr0 + mi * 16 + kg * 4 + j;
      if (EPI == 0) {
        float ps = 0.0f;
#pragma unroll
        for (int ni = 0; ni < 4; ++ni) {
          const float v = acc[mi][ni][j];
          ps += v * v;
          Cb[(size_t)r * N + cc0 + ni * 16 + idx] = __float2bfloat16(v);
        }
        ps += __shfl_xor(ps, 1, 64);
        ps += __shfl_xor(ps, 2, 64);
        ps += __shfl_xor(ps, 4, 64);
        ps += __shfl_xor(ps, 8, 64);
        if (idx == 0) atomicAdd(ss + r, ps);
      } else {
        const float sc = 1.0f / fmaxf(sqrtf(ss[r]), 1e-12f);
#pragma unroll
        for (int ni = 0; ni < 4; ++ni) {
          const size_t off = (size_t)r * N + cc0 + ni * 16 + idx;
          if (EPI == 1) {
            const float v = acc[mi][ni][j] * sc;
            const float ge =
                0.5f * v * (1.0f + erff(v * 0.70710678118654752f));
            Cb[off] = __float2bfloat16(ge);
          } else {
            Cf[off] = acc[mi][ni][j] + sc * __bfloat162float(C1[off]);
          }
        }
      }
    }
  }
}

extern "C" void kernel_launch(void* const* d_in, const int* in_sizes, int n_in,
                              void* d_out, int out_size, void* d_ws,
                              size_t ws_size, hipStream_t stream) {
  const float* x = (const float*)d_in[0];
  const float* cw = (const float*)d_in[1];
  const float* cb = (const float*)d_in[2];
  const float* qw = (const float*)d_in[3];
  const float* w1 = (const float*)d_in[4];
  const float* w2 = (const float*)d_in[5];
  float* out = (float*)d_out;

  // ws layout (high-water 135.54 MB, under proven-safe 135.79 MB):
  //   [0, 64Mi)        x_conv bf16, reused as g (gelu out) after GEMM1
  //   [64Mi, 128Mi)    C1 bf16 (pre-normalize q-GEMM output; lives to GEMM3)
  //   [128Mi, +512K)   weight slot A (bf16)
  //   [+512K, +1M)     weight slot B (bf16)
  //   [+1M, +1M+8K)    cwt f32 [4][512]
  //   [+1M+8K, +1.25M) ss f32 [ML] row sum-of-squares
  char* ws = (char*)d_ws;
  __hip_bfloat16* xconv = (__hip_bfloat16*)ws;
  __hip_bfloat16* C1 = (__hip_bfloat16*)(ws + (size_t)67108864);
  __hip_bfloat16* wA = (__hip_bfloat16*)(ws + (size_t)134217728);
  __hip_bfloat16* wB = wA + DIM * DIM;
  float* cwt = (float*)(ws + (size_t)134217728 + 1048576);
  float* ss = (float*)(ws + (size_t)134217728 + 1048576 + 8192);
  __hip_bfloat16* g = xconv;  // alias: x_conv dead after GEMM1

  const int gemm_grid = (ML / 128) * (DIM / 128);  // 2048 (%8==0 for T1)

  zero_ss<<<ML / 256, 256, 0, stream>>>(ss);
  prep_w<<<DIM * DIM / 256, 256, 0, stream>>>(qw, wA, 0, cw, cwt);
  prep_w<<<DIM * DIM / 256, 256, 0, stream>>>(w1, wB, 1, nullptr, nullptr);
  conv_cast_kernel<<<ML * (DIM / 4) / 256, 256, 0, stream>>>(x, cwt, cb, xconv);
  // GEMM1: C1 = x_conv @ q_w^T (bf16) + row sumsq -> ss
  gemm_bt<0><<<gemm_grid, 256, 0, stream>>>(xconv, wA, nullptr, C1, nullptr,
                                            ss, ML, DIM, DIM);
  prep_w<<<DIM * DIM / 256, 256, 0, stream>>>(w2, wA, 1, nullptr, nullptr);
  // GEMM2: g = gelu(sc * (C1 @ w1)) -> bf16 (into x_conv's region)
  gemm_bt<1><<<gemm_grid, 256, 0, stream>>>(C1, wB, nullptr, g, nullptr, ss,
                                            ML, DIM, DIM);
  // GEMM3: out = sc*C1 + g @ w2 -> f32
  gemm_bt<2><<<gemm_grid, 256, 0, stream>>>(g, wA, out, nullptr, C1, ss, ML,
                                            DIM, DIM);
}

// Round 5
// 292.910 us; speedup vs baseline: 1.7014x; 1.0049x over previous
//
#include <hip/hip_runtime.h>
#include <hip/hip_bf16.h>

#define DIM 512
#define BB 8
#define LL 8192
#define ML (BB * LL)  // 65536 rows

typedef __attribute__((ext_vector_type(4))) float f32x4;
typedef __attribute__((ext_vector_type(8))) short short8;

__device__ __forceinline__ void gl_lds16(const __hip_bfloat16* g, __hip_bfloat16* l) {
  __builtin_amdgcn_global_load_lds(
      (const __attribute__((address_space(1))) void*)g,
      (__attribute__((address_space(3))) void*)l, 16, 0, 0);
}

__device__ __forceinline__ unsigned short bf16_bits(float f) {
  __hip_bfloat16 h = __float2bfloat16(f);
  return *reinterpret_cast<unsigned short*>(&h);
}

// ---------------- zero the row-sumsq accumulator (deterministic, no memset) -
__global__ void zero_ss(float* __restrict__ ss) {
  ss[blockIdx.x * 256 + threadIdx.x] = 0.0f;
}

// ---------------- depthwise causal conv (K=4, left pad 3) + cast to bf16 ----
__global__ void conv_cast_kernel(const float* __restrict__ x,
                                 const float* __restrict__ cwt,
                                 const float* __restrict__ cb,
                                 __hip_bfloat16* __restrict__ xc) {
  const int tid = blockIdx.x * 256 + threadIdx.x;
  const int d = (tid & 127) << 2;  // 0..508 step 4
  const int bl = tid >> 7;
  const int l = bl & (LL - 1);
  float4 acc = *(const float4*)(cb + d);
  float4 w[4];
#pragma unroll
  for (int k = 0; k < 4; ++k) w[k] = *(const float4*)(cwt + k * DIM + d);
#pragma unroll
  for (int k = 0; k < 4; ++k) {
    if (l - 3 + k >= 0) {
      const float4 xv = *(const float4*)(x + (size_t)(bl - 3 + k) * DIM + d);
      acc.x += xv.x * w[k].x;
      acc.y += xv.y * w[k].y;
      acc.z += xv.z * w[k].z;
      acc.w += xv.w * w[k].w;
    }
  }
  ushort4 o;
  o.x = bf16_bits(acc.x);
  o.y = bf16_bits(acc.y);
  o.z = bf16_bits(acc.z);
  o.w = bf16_bits(acc.w);
  *(ushort4*)((unsigned short*)xc + (size_t)bl * DIM + d) = o;
}

// ---------------- weight prep: cast (or transpose-cast) one 512x512 weight --
__global__ void prep_w(const float* __restrict__ src,
                       __hip_bfloat16* __restrict__ dst, int transpose,
                       const float* __restrict__ cw, float* __restrict__ cwt) {
  const int i = blockIdx.x * 256 + threadIdx.x;  // 0..262143
  if (transpose)
    dst[(size_t)(i & 511) * DIM + (i >> 9)] = __float2bfloat16(src[i]);
  else
    dst[i] = __float2bfloat16(src[i]);
  if (cwt != nullptr && i < DIM * 4) cwt[(i & 3) * DIM + (i >> 2)] = cw[i];
}

// ---------------- GEMM: C[M,N] = A[M,K](bf16) @ Bt[N,K](bf16)^T, f32 acc ----
// 128x128 tile, BK=32, 4 waves (2x2). T4 pipeline: 3 LDS buffers, depth-2
// prefetch, raw s_barrier + counted vmcnt (never 0 in steady state).
// T2 both-sides XOR chunk-swizzle, T1 XCD-chunked block swizzle, T5 setprio.
// EPI 0: write C1 bf16 + per-row sum-of-squares atomics into ss
// EPI 1: v *= 1/max(sqrt(ss[r]),eps); exact GELU -> bf16
// EPI 2: out f32 = v + (1/max(sqrt(ss[r]),eps)) * C1_bf16[off]  (residual q)
template <int EPI>
__global__ __launch_bounds__(256) void gemm_bt(
    const __hip_bfloat16* __restrict__ A, const __hip_bfloat16* __restrict__ Bt,
    float* __restrict__ Cf, __hip_bfloat16* __restrict__ Cb,
    const __hip_bfloat16* __restrict__ C1, float* __restrict__ ss, int M,
    int N, int K) {
  __shared__ __hip_bfloat16 sA[3][128 * 32];
  __shared__ __hip_bfloat16 sB[3][128 * 32];
  // T1: XCD-chunked swizzle (gridDim %8 == 0 here: 2048)
  const int nbn = N >> 7;
  const int bid = blockIdx.x;
  const int swz = (bid & 7) * (gridDim.x >> 3) + (bid >> 3);
  const int bm = swz / nbn;
  const int bn = swz - bm * nbn;
  const int tid = threadIdx.x;
  const int wv = tid >> 6, ln = tid & 63;
  const int wr = wv >> 1, wc = wv & 1;
  const int idx = ln & 15, kg = ln >> 4;
  const size_t rowA = (size_t)bm * 128, rowB = (size_t)bn * 128;

  f32x4 acc[4][4] = {};

  // staging: slot s = (wv*2+i)*64 + ln -> LDS bytes [s*16, s*16+16)
  // row = s>>2, chunk kc = s&3. T2: LDS slot (row,kc) holds global chunk
  // kc ^ ((row>>1)&3); for this slot map that is (ln&3)^((ln>>3)&3).
  const int r0 = (wv * 2 + 0) * 16 + (ln >> 2);
  const int r1 = (wv * 2 + 1) * 16 + (ln >> 2);
  const int kcl = (((ln & 3) ^ ((ln >> 3) & 3)) << 3);  // elements
  // read side: global chunk kg at row lives in LDS chunk kg ^ ((idx>>1)&3)
  const int kgx = ((kg ^ ((idx >> 1) & 3)) << 3);  // elements

  const __hip_bfloat16* gA0 = A + (rowA + r0) * K + kcl;
  const __hip_bfloat16* gA1 = A + (rowA + r1) * K + kcl;
  const __hip_bfloat16* gB0 = Bt + (rowB + r0) * K + kcl;
  const __hip_bfloat16* gB1 = Bt + (rowB + r1) * K + kcl;
  const int lo0 = (wv * 2 + 0) * 512, lo1 = (wv * 2 + 1) * 512;

  const int nt = K >> 5;  // 16 K-steps

#define STAGE(t, b)                          \
  do {                                       \
    const int k0_ = (t) << 5;                \
    gl_lds16(gA0 + k0_, &sA[(b)][lo0]);      \
    gl_lds16(gA1 + k0_, &sA[(b)][lo1]);      \
    gl_lds16(gB0 + k0_, &sB[(b)][lo0]);      \
    gl_lds16(gB1 + k0_, &sB[(b)][lo1]);      \
  } while (0)

  // prologue: fill buffers 0 and 1
  STAGE(0, 0);
  STAGE(1, 1);

  int rb = 0;  // read buffer; write buffer = (rb+2)%3
  for (int t = 0; t < nt; ++t) {
    // my stage(t) must have landed; stage(t+1) may remain in flight
    if (t + 1 < nt) {
      asm volatile("s_waitcnt vmcnt(4)" ::: "memory");
    } else {
      asm volatile("s_waitcnt vmcnt(0)" ::: "memory");
    }
    // all waves: stage(t) landed AND buf[(t-1)%3] fully consumed
    __builtin_amdgcn_s_barrier();
    if (t + 2 < nt) {
      const int wbuf = rb < 1 ? rb + 2 : rb - 1;  // (rb+2)%3
      STAGE(t + 2, wbuf);
    }
    short8 af[4], bfv[4];
#pragma unroll
    for (int mi = 0; mi < 4; ++mi)
      af[mi] = *(const short8*)(&sA[rb][(wr * 64 + mi * 16 + idx) * 32 + kgx]);
#pragma unroll
    for (int ni = 0; ni < 4; ++ni)
      bfv[ni] = *(const short8*)(&sB[rb][(wc * 64 + ni * 16 + idx) * 32 + kgx]);
    __builtin_amdgcn_s_setprio(1);
#pragma unroll
    for (int mi = 0; mi < 4; ++mi)
#pragma unroll
      for (int ni = 0; ni < 4; ++ni)
        acc[mi][ni] = __builtin_amdgcn_mfma_f32_16x16x32_bf16(
            af[mi], bfv[ni], acc[mi][ni], 0, 0, 0);
    __builtin_amdgcn_s_setprio(0);
    rb = rb == 2 ? 0 : rb + 1;
  }
#undef STAGE

  // epilogue: C/D layout col = lane&15, row = (lane>>4)*4 + j  [m89-verified]
  const int cr0 = (int)rowA + wr * 64;
  const int cc0 = (int)rowB + wc * 64;
#pragma unroll
  for (int mi = 0; mi < 4; ++mi) {
#pragma unroll
    for (int j = 0; j < 4; ++j) {
      const int r = cr0 + mi * 16 + kg * 4 + j;
      if (EPI == 0) {
        float ps = 0.0f;
#pragma unroll
        for (int ni = 0; ni < 4; ++ni) {
          const float v = acc[mi][ni][j];
          ps += v * v;
          Cb[(size_t)r * N + cc0 + ni * 16 + idx] = __float2bfloat16(v);
        }
        ps += __shfl_xor(ps, 1, 64);
        ps += __shfl_xor(ps, 2, 64);
        ps += __shfl_xor(ps, 4, 64);
        ps += __shfl_xor(ps, 8, 64);
        if (idx == 0) atomicAdd(ss + r, ps);
      } else {
        const float sc = 1.0f / fmaxf(sqrtf(ss[r]), 1e-12f);
#pragma unroll
        for (int ni = 0; ni < 4; ++ni) {
          const size_t off = (size_t)r * N + cc0 + ni * 16 + idx;
          if (EPI == 1) {
            const float v = acc[mi][ni][j] * sc;
            const float ge =
                0.5f * v * (1.0f + erff(v * 0.70710678118654752f));
            Cb[off] = __float2bfloat16(ge);
          } else {
            Cf[off] = acc[mi][ni][j] + sc * __bfloat162float(C1[off]);
          }
        }
      }
    }
  }
}

extern "C" void kernel_launch(void* const* d_in, const int* in_sizes, int n_in,
                              void* d_out, int out_size, void* d_ws,
                              size_t ws_size, hipStream_t stream) {
  const float* x = (const float*)d_in[0];
  const float* cw = (const float*)d_in[1];
  const float* cb = (const float*)d_in[2];
  const float* qw = (const float*)d_in[3];
  const float* w1 = (const float*)d_in[4];
  const float* w2 = (const float*)d_in[5];
  float* out = (float*)d_out;

  // ws layout (high-water 135.54 MB, under proven-safe 135.79 MB):
  //   [0, 64Mi)        x_conv bf16, reused as g (gelu out) after GEMM1
  //   [64Mi, 128Mi)    C1 bf16 (pre-normalize q-GEMM output; lives to GEMM3)
  //   [128Mi, +512K)   weight slot A (bf16)
  //   [+512K, +1M)     weight slot B (bf16)
  //   [+1M, +1M+8K)    cwt f32 [4][512]
  //   [+1M+8K, +1.25M) ss f32 [ML] row sum-of-squares
  char* ws = (char*)d_ws;
  __hip_bfloat16* xconv = (__hip_bfloat16*)ws;
  __hip_bfloat16* C1 = (__hip_bfloat16*)(ws + (size_t)67108864);
  __hip_bfloat16* wA = (__hip_bfloat16*)(ws + (size_t)134217728);
  __hip_bfloat16* wB = wA + DIM * DIM;
  float* cwt = (float*)(ws + (size_t)134217728 + 1048576);
  float* ss = (float*)(ws + (size_t)134217728 + 1048576 + 8192);
  __hip_bfloat16* g = xconv;  // alias: x_conv dead after GEMM1

  const int gemm_grid = (ML / 128) * (DIM / 128);  // 2048 (%8==0 for T1)

  zero_ss<<<ML / 256, 256, 0, stream>>>(ss);
  prep_w<<<DIM * DIM / 256, 256, 0, stream>>>(qw, wA, 0, cw, cwt);
  prep_w<<<DIM * DIM / 256, 256, 0, stream>>>(w1, wB, 1, nullptr, nullptr);
  conv_cast_kernel<<<ML * (DIM / 4) / 256, 256, 0, stream>>>(x, cwt, cb, xconv);
  // GEMM1: C1 = x_conv @ q_w^T (bf16) + row sumsq -> ss
  gemm_bt<0><<<gemm_grid, 256, 0, stream>>>(xconv, wA, nullptr, C1, nullptr,
                                            ss, ML, DIM, DIM);
  prep_w<<<DIM * DIM / 256, 256, 0, stream>>>(w2, wA, 1, nullptr, nullptr);
  // GEMM2: g = gelu(sc * (C1 @ w1)) -> bf16 (into x_conv's region)
  gemm_bt<1><<<gemm_grid, 256, 0, stream>>>(C1, wB, nullptr, g, nullptr, ss,
                                            ML, DIM, DIM);
  // GEMM3: out = sc*C1 + g @ w2 -> f32
  gemm_bt<2><<<gemm_grid, 256, 0, stream>>>(g, wA, out, nullptr, C1, ss, ML,
                                            DIM, DIM);
}